// Round 15
// baseline (83.278 us; speedup 1.0000x reference)
//
#include <hip/hip_runtime.h>

// YOLOv1 head post-process — R15: R14 + two latency cuts (no semantic change).
//  1) softmax divide work split across 98 threads (waves 0-1): thread
//     (cell,h) duplicates the cheap mx/exp/sum chain (bit-identical order)
//     but does only its half's 10 divides + 20 stores — the serial chain
//     gating the phase-1 barrier drops ~100 insts. Decode on waves 2-3.
//  2) phase-3 preloads all 5 class scores (10 independent ds_reads) before
//     the NMS loop — one latency wait instead of 5 serialized ones.
// Kept from R14 (81.65us best): direct-from-global phase 1 (no xs staging,
// 3 barriers), ubnd[] union bounds, v_readlane box broadcasts, dense
// coalesced phase-4 writer, division-free EXACT IoU ((double)inter >
// (double)udiv*(0.5+2^-25); product exact 24+25<=53 bits, midpoint ties
// round-to-even excluded by >), rnk-free ballot keep map, contested-set NMS,
// ballot adjacency over union rows.
// Carried equivalences (R1-R5, R8-R14 all passed):
//  * score < SCORE_T boxes only suppress even-lower-sorted boxes (all zeroed
//    by final score filter) -> NMS over score>=SCORE_T candidates exact.
//  * candidate => conf*(1/sum) >= SCORE_T in float (monotone) -> union mask
//    covers every candidate; non-union adj rows never semantically read.
//  * contested-set restriction exact (IoU symmetric).
//  * rank tie-break = box index ascending = jnp stable argsort(-scores).
//  * K>64 (prob ~0) falls back to ballot-greedy (exact).
// Softmax float-op sequence bit-identical to R1-R14 (duplication changes
// which thread computes, not the op sequence producing each value).

namespace {
constexpr int kS    = 7;
constexpr int kC    = 20;
constexpr int kFeat = 30;             // C + 5*BBOX
constexpr int kN    = 98;             // S*S*2 boxes
constexpr int kRows = kN * kC;        // 1960
constexpr int kOutF = kRows * 6;      // 11760 floats per batch
constexpr int kT    = 256;            // threads per block (4 waves)
constexpr float kScoreT = 0.05f;
constexpr double kIouCmp = 0.50000001490116119384765625;   // 0.5 + 2^-25
}

// exact threshold test for reference's  inter/max(uni,1e-9) > 0.5
__device__ __forceinline__ bool iou_gt(float ax1, float ay1, float ax2, float ay2,
                                       float bx1, float by1, float bx2, float by2) {
#pragma clang fp contract(off)
    float aa = fmaxf(ax2 - ax1, 0.f) * fmaxf(ay2 - ay1, 0.f);
    float ab = fmaxf(bx2 - bx1, 0.f) * fmaxf(by2 - by1, 0.f);
    float ix1 = fmaxf(ax1, bx1);
    float iy1 = fmaxf(ay1, by1);
    float ix2 = fminf(ax2, bx2);
    float iy2 = fminf(ay2, by2);
    float inter = fmaxf(ix2 - ix1, 0.f) * fmaxf(iy2 - iy1, 0.f);
    float udiv = fmaxf(aa + ab - inter, 1e-9f);
    return (double)inter > (double)udiv * kIouCmp;
}

__device__ __forceinline__ unsigned long long shfl64(unsigned long long v, int src) {
    unsigned lo = (unsigned)__shfl((int)(unsigned)(v & 0xffffffffull), src);
    unsigned hi = (unsigned)__shfl((int)(unsigned)(v >> 32), src);
    return ((unsigned long long)hi << 32) | lo;
}

// wave-uniform lane read on the scalar path (no LDS pipe)
__device__ __forceinline__ float readlane_f(float v, int l) {
    return __int_as_float(__builtin_amdgcn_readlane(__float_as_int(v), l));
}

__global__ __launch_bounds__(kT, 4) void yolo_head_kernel(const float* __restrict__ x,
                                                          float* __restrict__ out) {
    __shared__ float scT[kRows];                            // scores [c][n]
    __shared__ float ubnd[kN];                              // conf_k/sum per box
    __shared__ float x1s[kN], y1s[kN], x2s[kN], y2s[kN];    // SoA boxes
    __shared__ unsigned long long adjLo[kN], adjHi[kN];     // IoU>T rows (union only)
    __shared__ float csc[4][kN];                            // per-wave cand scores
    __shared__ unsigned short cid[4][kN];                   // per-wave cand box idx
    __shared__ unsigned short rid[4][64];                   // rank -> box idx
    __shared__ unsigned km[kC][4];                          // keep mask per class

    const int b   = blockIdx.x;
    const int tid = threadIdx.x;
    const float* xb = x + (size_t)b * (kS * kS * kFeat);

    // ---- phase 1: softmax split over 98 thr (waves 0-1) + decode (waves 2-3) ----
    if (tid < 2 * kS * kS) {
#pragma clang fp contract(off)
        const int cell = tid >> 1;                // adjacent threads share cell
        const int h    = tid & 1;                 // class half 0: c<10, 1: c>=10
        const float* p = xb + cell * kFeat;       // reads floats 0..19, 28..29
        float mx = p[0];
        for (int c = 1; c < kC; ++c) mx = fmaxf(mx, p[c]);
        float e[kC];
        float sum = 0.f;
        for (int c = 0; c < kC; ++c) { e[c] = expf(p[c] - mx); sum += e[c]; }
        const float conf0 = p[28], conf1 = p[29];
        for (int lc = 0; lc < kC / 2; ++lc) {
            const int c = (kC / 2) * h + lc;
            float pr = e[c] / sum;                // identical op as monolithic form
            scT[c * kN + 2 * cell]     = pr * conf0;
            scT[c * kN + 2 * cell + 1] = pr * conf1;
        }
        const float mp = 1.0f / sum;              // exp(0)=1 is the exact max of e[]
        if (h == 0) ubnd[2 * cell]     = conf0 * mp;
        else        ubnd[2 * cell + 1] = conf1 * mp;
    } else if (tid >= 128 && tid < 128 + kN) {
#pragma clang fp contract(off)
        const int n = tid - 128;
        const int cell = n >> 1, k = n & 1;
        const int gi = cell / kS, gj = cell % kS;   // gy=gi, gx=gj
        const float* p = xb + cell * kFeat + kC + 4 * k;   // reads floats 20..27
        float cx = (p[0] + (float)gj) / 7.0f;
        float cy = (p[1] + (float)gi) / 7.0f;
        float w = p[2], h2 = p[3];
        x1s[n] = fminf(fmaxf(cx - w * 0.5f, 0.f), 1.f) * 448.f;
        y1s[n] = fminf(fmaxf(cy - h2 * 0.5f, 0.f), 1.f) * 448.f;
        x2s[n] = fminf(fmaxf(cx + w * 0.5f, 0.f), 1.f) * 448.f;
        y2s[n] = fminf(fmaxf(cy + h2 * 0.5f, 0.f), 1.f) * 448.f;
    }
    __syncthreads();

    const int wv   = tid >> 6;
    const int lane = tid & 63;
    const bool hasB = (lane < kN - 64);
    const int nB   = hasB ? lane + 64 : 0;               // valid dummy for lane>=34

    // per-lane box coords in registers (stride-4B conflict-free LDS loads)
    const float aX1 = x1s[lane], aY1 = y1s[lane], aX2 = x2s[lane], aY2 = y2s[lane];
    const float bX1 = x1s[nB],  bY1 = y1s[nB],  bX2 = x2s[nB],  bY2 = y2s[nB];

    // ---- phase 2: union mask + ballot adjacency (ctz walk, round-robin waves) ----
    {
        const bool uA = ubnd[lane] >= kScoreT;
        const bool uB = hasB && (ubnd[nB] >= kScoreT);
        const unsigned long long ULo = __ballot(uA);
        const unsigned long long UHi = __ballot(uB);
        int idx = 0;
        unsigned long long m = ULo;
        while (m) {
            const int i = __builtin_ctzll(m);
            m &= m - 1;
            if ((idx++ & 3) != wv) continue;            // round-robin over waves
            const float iX1 = readlane_f(aX1, i);       // SALU broadcast, no LDS
            const float iY1 = readlane_f(aY1, i);
            const float iX2 = readlane_f(aX2, i);
            const float iY2 = readlane_f(aY2, i);
            const bool oA = iou_gt(iX1, iY1, iX2, iY2, aX1, aY1, aX2, aY2);
            const bool oB = hasB && iou_gt(iX1, iY1, iX2, iY2, bX1, bY1, bX2, bY2);
            const unsigned long long rLo = __ballot(oA);
            const unsigned long long rHi = __ballot(oB);
            if (lane == 0) { adjLo[i] = rLo; adjHi[i] = rHi; }
        }
        m = UHi;
        while (m) {
            const int j = __builtin_ctzll(m);
            m &= m - 1;
            if ((idx++ & 3) != wv) continue;
            const int i = 64 + j;
            const float iX1 = readlane_f(bX1, j);
            const float iY1 = readlane_f(bY1, j);
            const float iX2 = readlane_f(bX2, j);
            const float iY2 = readlane_f(bY2, j);
            const bool oA = iou_gt(iX1, iY1, iX2, iY2, aX1, aY1, aX2, aY2);
            const bool oB = hasB && iou_gt(iX1, iY1, iX2, iY2, bX1, bY1, bX2, bY2);
            const unsigned long long rLo = __ballot(oA);
            const unsigned long long rHi = __ballot(oB);
            if (lane == 0) { adjLo[i] = rLo; adjHi[i] = rHi; }
        }
    }
    __syncthreads();

    // ---- phase 3: per-class NMS with contested-set restriction (5 classes/wave) ----
    {
        const unsigned long long rowLoA = adjLo[lane], rowHiA = adjHi[lane];
        const unsigned long long rowLoB = adjLo[nB],   rowHiB = adjHi[nB];
        const unsigned long long selfA  = 1ull << lane;  // A self in Lo; B self in Hi bit `lane`
        const unsigned long long lt     = (1ull << lane) - 1ull;

        // preload this wave's 5 class scores: 10 independent ds_reads
        float ps0[5], ps1[5];
#pragma unroll
        for (int pass = 0; pass < 5; ++pass) {
            const int c = wv + 4 * pass;
            ps0[pass] = scT[c * kN + lane];
            ps1[pass] = hasB ? scT[c * kN + 64 + lane] : 0.f;
        }

        for (int pass = 0; pass < 5; ++pass) {
            const int c = wv + 4 * pass;                 // always < 20
            const float s0 = ps0[pass];
            const float s1 = ps1[pass];
            const bool  c0 = (s0 >= kScoreT);
            const bool  c1 = hasB && (s1 >= kScoreT);
            const unsigned long long candLo = __ballot(c0);
            const unsigned long long candHi = __ballot(c1);
            const int K = __popcll(candLo) + __popcll(candHi);

            // contested = candidate overlapping another candidate
            const bool t0 = c0 && ((((rowLoA & candLo) & ~selfA) | (rowHiA & candHi)) != 0ull);
            const bool t1 = c1 && (((rowLoB & candLo) | ((rowHiB & candHi) & ~selfA)) != 0ull);
            const unsigned long long conLo = __ballot(t0);
            const unsigned long long conHi = __ballot(t1);

            unsigned long long keepLo, keepHi;
            if ((conLo | conHi) == 0ull) {
                keepLo = candLo; keepHi = candHi;        // nothing can suppress
            } else if (K <= 64) {
                // rank + scan over the contested set S only (KS <= 64)
                const int KS0 = __popcll(conLo);
                const int KS  = KS0 + __popcll(conHi);
                int q0 = 0, q1 = 0;
                if (t0) { q0 = __popcll(conLo & lt);       csc[wv][q0] = s0; cid[wv][q0] = (unsigned short)lane; }
                if (t1) { q1 = KS0 + __popcll(conHi & lt); csc[wv][q1] = s1; cid[wv][q1] = (unsigned short)(lane + 64); }
                __builtin_amdgcn_wave_barrier();
                const bool  act = (lane < KS);
                const float sp  = act ? csc[wv][lane] : 0.f;
                int rp = 0;
                for (int q = 0; q < KS; ++q) {
                    const float sq = csc[wv][q];           // broadcast read
                    rp += ((sq > sp) || ((sq == sp) && (q < lane))) ? 1 : 0;
                }
                if (act) rid[wv][rp] = cid[wv][lane];
                __builtin_amdgcn_wave_barrier();
                const int myb = act ? (int)rid[wv][lane] : 0;
                const unsigned long long rLo = adjLo[myb];
                const unsigned long long rHi = adjHi[myb];
                unsigned long long supLo = 0, supHi = 0, keepM = 0;
                for (int r = 0; r < KS; ++r) {
                    const int bi = __shfl(myb, r);         // indep of sup chain
                    const unsigned long long qLo = shfl64(rLo, r);
                    const unsigned long long qHi = shfl64(rHi, r);
                    const unsigned long long word = (bi & 64) ? supHi : supLo;
                    const unsigned long long bit  = (word >> (bi & 63)) & 1ull;
                    const unsigned long long take = bit - 1ull;  // ~0 if alive
                    keepM |= (1ull << r) & take;
                    supLo |= qLo & take;
                    supHi |= qHi & take;
                }
                // keep-bit of contested position `lane` = keepM bit rp ->
                // broadcast back to position space with one ballot
                const unsigned long long posKeep = __ballot(act && ((keepM >> rp) & 1ull));
                const bool k0 = t0 && ((posKeep >> q0) & 1ull);
                const bool k1 = t1 && ((posKeep >> q1) & 1ull);
                keepLo = (candLo & ~conLo) | __ballot(k0);
                keepHi = (candHi & ~conHi) | __ballot(k1);
            } else {
                // fallback (K>64, prob ~0): ballot-greedy over all candidates
                const int K0 = __popcll(candLo);
                int p0 = 0, p1 = 0;
                if (c0) { p0 = __popcll(candLo & lt);      csc[wv][p0] = s0; cid[wv][p0] = (unsigned short)lane; }
                if (c1) { p1 = K0 + __popcll(candHi & lt); csc[wv][p1] = s1; cid[wv][p1] = (unsigned short)(lane + 64); }
                __builtin_amdgcn_wave_barrier();
                bool al0 = c0, al1 = c1, k0 = false, k1 = false;
                for (;;) {
                    float bs; int bp;
                    if (al0 && (!al1 || s0 >= s1)) { bs = s0; bp = p0; }
                    else if (al1)                  { bs = s1; bp = p1; }
                    else                           { bs = -1e30f; bp = 1 << 20; }
                    for (int off = 32; off; off >>= 1) {
                        const float os = __shfl_xor(bs, off);
                        const int   op = __shfl_xor(bp, off);
                        if (os > bs || (os == bs && op < bp)) { bs = os; bp = op; }
                    }
                    if (bp >= (1 << 20)) break;
                    const int bi = cid[wv][bp];            // wave-uniform
                    float kx1, ky1, kx2, ky2;
                    if (bi < 64) {
                        kx1 = readlane_f(aX1, bi); ky1 = readlane_f(aY1, bi);
                        kx2 = readlane_f(aX2, bi); ky2 = readlane_f(aY2, bi);
                    } else {
                        kx1 = readlane_f(bX1, bi - 64); ky1 = readlane_f(bY1, bi - 64);
                        kx2 = readlane_f(bX2, bi - 64); ky2 = readlane_f(bY2, bi - 64);
                    }
                    if (bp == p0 && al0) { k0 = true; al0 = false; }
                    if (bp == p1 && al1) { k1 = true; al1 = false; }
                    if (al0 && iou_gt(kx1, ky1, kx2, ky2, aX1, aY1, aX2, aY2)) al0 = false;
                    if (al1 && iou_gt(kx1, ky1, kx2, ky2, bX1, bY1, bX2, bY2)) al1 = false;
                }
                keepLo = __ballot(k0);
                keepHi = __ballot(k1);
            }
            if (lane == 0) {
                km[c][0] = (unsigned)keepLo;
                km[c][1] = (unsigned)(keepLo >> 32);
                km[c][2] = (unsigned)keepHi;
                km[c][3] = (unsigned)(keepHi >> 32);
            }
        }
    }
    __syncthreads();

    // ---- phase 4: dense coalesced writer — thread j emits rows 2j,2j+1 ----
    for (int j = tid; j < kRows / 2; j += kT) {
        const int n = j / 10;                 // rows 2j,2j+1 share n
        const int c0i = 2 * (j % 10);
        const int c1i = c0i + 1;
        const float sA = scT[c0i * kN + n];
        const float sB = scT[c1i * kN + n];
        const float bbx = x1s[n], bby = y1s[n], bbz = x2s[n], bbw = y2s[n];
        const float mA = ((km[c0i][n >> 5] >> (n & 31)) & 1u) ? 1.f : 0.f;
        const float mB = ((km[c1i][n >> 5] >> (n & 31)) & 1u) ? 1.f : 0.f;
        float* ob = out + (size_t)b * kOutF + (size_t)12 * j;
        float4 q0, q1, q2;
        q0.x = mA * (float)c0i; q0.y = mA * bbx; q0.z = mA * bby; q0.w = mA * bbz;
        q1.x = mA * bbw;        q1.y = mA * sA;  q1.z = mB * (float)c1i; q1.w = mB * bbx;
        q2.x = mB * bby;        q2.y = mB * bbz; q2.z = mB * bbw;        q2.w = mB * sB;
        reinterpret_cast<float4*>(ob)[0] = q0;
        reinterpret_cast<float4*>(ob)[1] = q1;
        reinterpret_cast<float4*>(ob)[2] = q2;
    }
}

extern "C" void kernel_launch(void* const* d_in, const int* in_sizes, int n_in,
                              void* d_out, int out_size, void* d_ws, size_t ws_size,
                              hipStream_t stream) {
    const float* x = (const float*)d_in[0];
    float* out = (float*)d_out;
    const int B = in_sizes[0] / (kS * kS * kFeat);   // 1024
    hipLaunchKernelGGL(yolo_head_kernel, dim3(B), dim3(kT), 0, stream, x, out);
}

// Round 16
// 82.021 us; speedup vs baseline: 1.0153x; 1.0153x over previous
//
#include <hip/hip_runtime.h>

// YOLOv1 head post-process — R16 = R14 exactly (best measured: 81.65us), the
// session's final kernel. R15's softmax-split regressed (+1.6us: duplicated
// exp chains cost more issue than the critical path saved) — reverted.
// Structure: 256 thr/block, grid = B = 1024, 16 waves/CU (measured optimum:
// R10 showed fewer => latency-bound; R11 showed more via duplication =>
// linear cost). Kernel ~25us vs ~56us fixed harness poison-fill overhead.
// Features (each A/B-measured):
//  * phase 1 direct-from-global: softmax (floats 0-19,28-29) and decode
//    (20-27) read disjoint slices; no LDS staging; 3 barriers total (R14).
//  * ubnd[n] = conf_k*(1/sum): one ds_read union-candidate test (R14).
//  * v_readlane wave-uniform box broadcasts — off the LDS pipe (R14).
//  * ballot-built IoU adjacency over union rows only, ctz walk (R8/R13).
//  * contested-set NMS: candidate overlapping no other candidate is kept;
//    NMS(cand) = (cand\S) ∪ NMS(S), rank+register-shfl scan over S (R8).
//  * division-free EXACT IoU: RN(inter/udiv)>0.5 <=> (double)inter >
//    (double)udiv*(0.5+2^-25) — product exact (24+25<=53 bits), midpoint
//    ties round-to-even excluded by strict > (R12/R13).
//  * rnk-free keep mapping via position-space ballot (R12/R13).
//  * dense coalesced phase-4 writer: thread j -> contiguous rows 2j,2j+1,
//    3x float4 (R9; R12's fused 480B-stride writer regressed).
// Carried equivalences (R1-R5, R8-R15 all passed, absmax 9.8e-4 ≪ thr 8.96):
//  * score < SCORE_T boxes only suppress even-lower-sorted boxes (all zeroed
//    by final score filter) -> NMS over score>=SCORE_T candidates exact.
//  * candidate => conf*(1/sum) >= SCORE_T in float (monotone) -> union mask
//    covers every candidate; non-union adj rows never semantically read.
//  * contested-set restriction exact (IoU symmetric).
//  * rank tie-break = box index ascending = jnp stable argsort(-scores).
//  * K>64 (prob ~0) falls back to ballot-greedy (exact).
// Softmax float-op sequence bit-identical to the reference op order.

namespace {
constexpr int kS    = 7;
constexpr int kC    = 20;
constexpr int kFeat = 30;             // C + 5*BBOX
constexpr int kN    = 98;             // S*S*2 boxes
constexpr int kRows = kN * kC;        // 1960
constexpr int kOutF = kRows * 6;      // 11760 floats per batch
constexpr int kT    = 256;            // threads per block (4 waves)
constexpr float kScoreT = 0.05f;
constexpr double kIouCmp = 0.50000001490116119384765625;   // 0.5 + 2^-25
}

// exact threshold test for reference's  inter/max(uni,1e-9) > 0.5
__device__ __forceinline__ bool iou_gt(float ax1, float ay1, float ax2, float ay2,
                                       float bx1, float by1, float bx2, float by2) {
#pragma clang fp contract(off)
    float aa = fmaxf(ax2 - ax1, 0.f) * fmaxf(ay2 - ay1, 0.f);
    float ab = fmaxf(bx2 - bx1, 0.f) * fmaxf(by2 - by1, 0.f);
    float ix1 = fmaxf(ax1, bx1);
    float iy1 = fmaxf(ay1, by1);
    float ix2 = fminf(ax2, bx2);
    float iy2 = fminf(ay2, by2);
    float inter = fmaxf(ix2 - ix1, 0.f) * fmaxf(iy2 - iy1, 0.f);
    float udiv = fmaxf(aa + ab - inter, 1e-9f);
    return (double)inter > (double)udiv * kIouCmp;
}

__device__ __forceinline__ unsigned long long shfl64(unsigned long long v, int src) {
    unsigned lo = (unsigned)__shfl((int)(unsigned)(v & 0xffffffffull), src);
    unsigned hi = (unsigned)__shfl((int)(unsigned)(v >> 32), src);
    return ((unsigned long long)hi << 32) | lo;
}

// wave-uniform lane read on the scalar path (no LDS pipe)
__device__ __forceinline__ float readlane_f(float v, int l) {
    return __int_as_float(__builtin_amdgcn_readlane(__float_as_int(v), l));
}

__global__ __launch_bounds__(kT, 4) void yolo_head_kernel(const float* __restrict__ x,
                                                          float* __restrict__ out) {
    __shared__ float scT[kRows];                            // scores [c][n]
    __shared__ float ubnd[kN];                              // conf_k/sum per box
    __shared__ float x1s[kN], y1s[kN], x2s[kN], y2s[kN];    // SoA boxes
    __shared__ unsigned long long adjLo[kN], adjHi[kN];     // IoU>T rows (union only)
    __shared__ float csc[4][kN];                            // per-wave cand scores
    __shared__ unsigned short cid[4][kN];                   // per-wave cand box idx
    __shared__ unsigned short rid[4][64];                   // rank -> box idx
    __shared__ unsigned km[kC][4];                          // keep mask per class

    const int b   = blockIdx.x;
    const int tid = threadIdx.x;
    const float* xb = x + (size_t)b * (kS * kS * kFeat);

    // ---- phase 1: direct-from-global softmax (0-48) + box decode (64-161) ----
    if (tid < kS * kS) {
#pragma clang fp contract(off)
        const int cell = tid;
        const float* p = xb + cell * kFeat;       // reads floats 0..19, 28..29
        float mx = p[0];
        for (int c = 1; c < kC; ++c) mx = fmaxf(mx, p[c]);
        float e[kC];
        float sum = 0.f;
        for (int c = 0; c < kC; ++c) { e[c] = expf(p[c] - mx); sum += e[c]; }
        const float conf0 = p[28], conf1 = p[29];
        for (int c = 0; c < kC; ++c) {
            float pr = e[c] / sum;
            scT[c * kN + 2 * cell]     = pr * conf0;
            scT[c * kN + 2 * cell + 1] = pr * conf1;
        }
        const float mp = 1.0f / sum;              // exp(0)=1 is the exact max of e[]
        ubnd[2 * cell]     = conf0 * mp;          // same mul as old conf*maxp test
        ubnd[2 * cell + 1] = conf1 * mp;
    } else if (tid >= 64 && tid < 64 + kN) {
#pragma clang fp contract(off)
        const int n = tid - 64;
        const int cell = n >> 1, k = n & 1;
        const int gi = cell / kS, gj = cell % kS;   // gy=gi, gx=gj
        const float* p = xb + cell * kFeat + kC + 4 * k;   // reads floats 20..27
        float cx = (p[0] + (float)gj) / 7.0f;
        float cy = (p[1] + (float)gi) / 7.0f;
        float w = p[2], h2 = p[3];
        x1s[n] = fminf(fmaxf(cx - w * 0.5f, 0.f), 1.f) * 448.f;
        y1s[n] = fminf(fmaxf(cy - h2 * 0.5f, 0.f), 1.f) * 448.f;
        x2s[n] = fminf(fmaxf(cx + w * 0.5f, 0.f), 1.f) * 448.f;
        y2s[n] = fminf(fmaxf(cy + h2 * 0.5f, 0.f), 1.f) * 448.f;
    }
    __syncthreads();

    const int wv   = tid >> 6;
    const int lane = tid & 63;
    const bool hasB = (lane < kN - 64);
    const int nB   = hasB ? lane + 64 : 0;               // valid dummy for lane>=34

    // per-lane box coords in registers (stride-4B conflict-free LDS loads)
    const float aX1 = x1s[lane], aY1 = y1s[lane], aX2 = x2s[lane], aY2 = y2s[lane];
    const float bX1 = x1s[nB],  bY1 = y1s[nB],  bX2 = x2s[nB],  bY2 = y2s[nB];

    // ---- phase 2: union mask + ballot adjacency (ctz walk, round-robin waves) ----
    {
        const bool uA = ubnd[lane] >= kScoreT;
        const bool uB = hasB && (ubnd[nB] >= kScoreT);
        const unsigned long long ULo = __ballot(uA);
        const unsigned long long UHi = __ballot(uB);
        int idx = 0;
        unsigned long long m = ULo;
        while (m) {
            const int i = __builtin_ctzll(m);
            m &= m - 1;
            if ((idx++ & 3) != wv) continue;            // round-robin over waves
            const float iX1 = readlane_f(aX1, i);       // SALU broadcast, no LDS
            const float iY1 = readlane_f(aY1, i);
            const float iX2 = readlane_f(aX2, i);
            const float iY2 = readlane_f(aY2, i);
            const bool oA = iou_gt(iX1, iY1, iX2, iY2, aX1, aY1, aX2, aY2);
            const bool oB = hasB && iou_gt(iX1, iY1, iX2, iY2, bX1, bY1, bX2, bY2);
            const unsigned long long rLo = __ballot(oA);
            const unsigned long long rHi = __ballot(oB);
            if (lane == 0) { adjLo[i] = rLo; adjHi[i] = rHi; }
        }
        m = UHi;
        while (m) {
            const int j = __builtin_ctzll(m);
            m &= m - 1;
            if ((idx++ & 3) != wv) continue;
            const int i = 64 + j;
            const float iX1 = readlane_f(bX1, j);
            const float iY1 = readlane_f(bY1, j);
            const float iX2 = readlane_f(bX2, j);
            const float iY2 = readlane_f(bY2, j);
            const bool oA = iou_gt(iX1, iY1, iX2, iY2, aX1, aY1, aX2, aY2);
            const bool oB = hasB && iou_gt(iX1, iY1, iX2, iY2, bX1, bY1, bX2, bY2);
            const unsigned long long rLo = __ballot(oA);
            const unsigned long long rHi = __ballot(oB);
            if (lane == 0) { adjLo[i] = rLo; adjHi[i] = rHi; }
        }
    }
    __syncthreads();

    // ---- phase 3: per-class NMS with contested-set restriction (5 classes/wave) ----
    {
        const unsigned long long rowLoA = adjLo[lane], rowHiA = adjHi[lane];
        const unsigned long long rowLoB = adjLo[nB],   rowHiB = adjHi[nB];
        const unsigned long long selfA  = 1ull << lane;  // A self in Lo; B self in Hi bit `lane`
        const unsigned long long lt     = (1ull << lane) - 1ull;
        for (int pass = 0; pass < 5; ++pass) {
            const int c = wv + 4 * pass;                 // always < 20

            const float s0 = scT[c * kN + lane];
            const float s1 = hasB ? scT[c * kN + 64 + lane] : 0.f;
            const bool  c0 = (s0 >= kScoreT);
            const bool  c1 = hasB && (s1 >= kScoreT);
            const unsigned long long candLo = __ballot(c0);
            const unsigned long long candHi = __ballot(c1);
            const int K = __popcll(candLo) + __popcll(candHi);

            // contested = candidate overlapping another candidate
            const bool t0 = c0 && ((((rowLoA & candLo) & ~selfA) | (rowHiA & candHi)) != 0ull);
            const bool t1 = c1 && (((rowLoB & candLo) | ((rowHiB & candHi) & ~selfA)) != 0ull);
            const unsigned long long conLo = __ballot(t0);
            const unsigned long long conHi = __ballot(t1);

            unsigned long long keepLo, keepHi;
            if ((conLo | conHi) == 0ull) {
                keepLo = candLo; keepHi = candHi;        // nothing can suppress
            } else if (K <= 64) {
                // rank + scan over the contested set S only (KS <= 64)
                const int KS0 = __popcll(conLo);
                const int KS  = KS0 + __popcll(conHi);
                int q0 = 0, q1 = 0;
                if (t0) { q0 = __popcll(conLo & lt);       csc[wv][q0] = s0; cid[wv][q0] = (unsigned short)lane; }
                if (t1) { q1 = KS0 + __popcll(conHi & lt); csc[wv][q1] = s1; cid[wv][q1] = (unsigned short)(lane + 64); }
                __builtin_amdgcn_wave_barrier();
                const bool  act = (lane < KS);
                const float sp  = act ? csc[wv][lane] : 0.f;
                int rp = 0;
                for (int q = 0; q < KS; ++q) {
                    const float sq = csc[wv][q];           // broadcast read
                    rp += ((sq > sp) || ((sq == sp) && (q < lane))) ? 1 : 0;
                }
                if (act) rid[wv][rp] = cid[wv][lane];
                __builtin_amdgcn_wave_barrier();
                const int myb = act ? (int)rid[wv][lane] : 0;
                const unsigned long long rLo = adjLo[myb];
                const unsigned long long rHi = adjHi[myb];
                unsigned long long supLo = 0, supHi = 0, keepM = 0;
                for (int r = 0; r < KS; ++r) {
                    const int bi = __shfl(myb, r);         // indep of sup chain
                    const unsigned long long qLo = shfl64(rLo, r);
                    const unsigned long long qHi = shfl64(rHi, r);
                    const unsigned long long word = (bi & 64) ? supHi : supLo;
                    const unsigned long long bit  = (word >> (bi & 63)) & 1ull;
                    const unsigned long long take = bit - 1ull;  // ~0 if alive
                    keepM |= (1ull << r) & take;
                    supLo |= qLo & take;
                    supHi |= qHi & take;
                }
                // keep-bit of contested position `lane` = keepM bit rp ->
                // broadcast back to position space with one ballot
                const unsigned long long posKeep = __ballot(act && ((keepM >> rp) & 1ull));
                const bool k0 = t0 && ((posKeep >> q0) & 1ull);
                const bool k1 = t1 && ((posKeep >> q1) & 1ull);
                keepLo = (candLo & ~conLo) | __ballot(k0);
                keepHi = (candHi & ~conHi) | __ballot(k1);
            } else {
                // fallback (K>64, prob ~0): ballot-greedy over all candidates
                const int K0 = __popcll(candLo);
                int p0 = 0, p1 = 0;
                if (c0) { p0 = __popcll(candLo & lt);      csc[wv][p0] = s0; cid[wv][p0] = (unsigned short)lane; }
                if (c1) { p1 = K0 + __popcll(candHi & lt); csc[wv][p1] = s1; cid[wv][p1] = (unsigned short)(lane + 64); }
                __builtin_amdgcn_wave_barrier();
                bool al0 = c0, al1 = c1, k0 = false, k1 = false;
                for (;;) {
                    float bs; int bp;
                    if (al0 && (!al1 || s0 >= s1)) { bs = s0; bp = p0; }
                    else if (al1)                  { bs = s1; bp = p1; }
                    else                           { bs = -1e30f; bp = 1 << 20; }
                    for (int off = 32; off; off >>= 1) {
                        const float os = __shfl_xor(bs, off);
                        const int   op = __shfl_xor(bp, off);
                        if (os > bs || (os == bs && op < bp)) { bs = os; bp = op; }
                    }
                    if (bp >= (1 << 20)) break;
                    const int bi = cid[wv][bp];            // wave-uniform
                    float kx1, ky1, kx2, ky2;
                    if (bi < 64) {
                        kx1 = readlane_f(aX1, bi); ky1 = readlane_f(aY1, bi);
                        kx2 = readlane_f(aX2, bi); ky2 = readlane_f(aY2, bi);
                    } else {
                        kx1 = readlane_f(bX1, bi - 64); ky1 = readlane_f(bY1, bi - 64);
                        kx2 = readlane_f(bX2, bi - 64); ky2 = readlane_f(bY2, bi - 64);
                    }
                    if (bp == p0 && al0) { k0 = true; al0 = false; }
                    if (bp == p1 && al1) { k1 = true; al1 = false; }
                    if (al0 && iou_gt(kx1, ky1, kx2, ky2, aX1, aY1, aX2, aY2)) al0 = false;
                    if (al1 && iou_gt(kx1, ky1, kx2, ky2, bX1, bY1, bX2, bY2)) al1 = false;
                }
                keepLo = __ballot(k0);
                keepHi = __ballot(k1);
            }
            if (lane == 0) {
                km[c][0] = (unsigned)keepLo;
                km[c][1] = (unsigned)(keepLo >> 32);
                km[c][2] = (unsigned)keepHi;
                km[c][3] = (unsigned)(keepHi >> 32);
            }
        }
    }
    __syncthreads();

    // ---- phase 4: dense coalesced writer — thread j emits rows 2j,2j+1 ----
    for (int j = tid; j < kRows / 2; j += kT) {
        const int n = j / 10;                 // rows 2j,2j+1 share n
        const int c0i = 2 * (j % 10);
        const int c1i = c0i + 1;
        const float sA = scT[c0i * kN + n];
        const float sB = scT[c1i * kN + n];
        const float bbx = x1s[n], bby = y1s[n], bbz = x2s[n], bbw = y2s[n];
        const float mA = ((km[c0i][n >> 5] >> (n & 31)) & 1u) ? 1.f : 0.f;
        const float mB = ((km[c1i][n >> 5] >> (n & 31)) & 1u) ? 1.f : 0.f;
        float* ob = out + (size_t)b * kOutF + (size_t)12 * j;
        float4 q0, q1, q2;
        q0.x = mA * (float)c0i; q0.y = mA * bbx; q0.z = mA * bby; q0.w = mA * bbz;
        q1.x = mA * bbw;        q1.y = mA * sA;  q1.z = mB * (float)c1i; q1.w = mB * bbx;
        q2.x = mB * bby;        q2.y = mB * bbz; q2.z = mB * bbw;        q2.w = mB * sB;
        reinterpret_cast<float4*>(ob)[0] = q0;
        reinterpret_cast<float4*>(ob)[1] = q1;
        reinterpret_cast<float4*>(ob)[2] = q2;
    }
}

extern "C" void kernel_launch(void* const* d_in, const int* in_sizes, int n_in,
                              void* d_out, int out_size, void* d_ws, size_t ws_size,
                              hipStream_t stream) {
    const float* x = (const float*)d_in[0];
    float* out = (float*)d_out;
    const int B = in_sizes[0] / (kS * kS * kFeat);   // 1024
    hipLaunchKernelGGL(yolo_head_kernel, dim3(B), dim3(kT), 0, stream, x, out);
}